// Round 5
// baseline (2060.974 us; speedup 1.0000x reference)
//
#include <hip/hip_runtime.h>
#include <hip/hip_bf16.h>
#include <math.h>

typedef __attribute__((ext_vector_type(8))) short s16x8;
typedef __attribute__((ext_vector_type(4))) float f32x4;

static __device__ __forceinline__ float b2f(unsigned short u) {
    union { unsigned int u; float f; } x; x.u = ((unsigned int)u) << 16; return x.f;
}
static __device__ __forceinline__ unsigned short f2b(float f) {
    __hip_bfloat16 h = __float2bfloat16(f);
    return *reinterpret_cast<unsigned short*>(&h);
}
static __device__ __forceinline__ float gelu_exact(float x) {
    return 0.5f * x * (1.0f + erff(x * 0.70710678118654752f));
}

// ---------------------------------------------------------------------------
// f32 -> bf16 element-wise convert (weights), 4 elems/thread
// ---------------------------------------------------------------------------
__global__ __launch_bounds__(256) void cvt_kernel(
    const float* __restrict__ in, unsigned short* __restrict__ outp, int n)
{
    int i = (blockIdx.x * 256 + threadIdx.x) * 4;
    if (i >= n) return;
    float4 v = *(const float4*)(in + i);
    uint2 d;
    d.x = (unsigned int)f2b(v.x) | ((unsigned int)f2b(v.y) << 16);
    d.y = (unsigned int)f2b(v.z) | ((unsigned int)f2b(v.w) << 16);
    *(uint2*)(outp + i) = d;
}

// ---------------------------------------------------------------------------
// LayerNorm: f32 input rows of 512 -> bf16 output. One wave per row.
// ---------------------------------------------------------------------------
__global__ __launch_bounds__(256) void ln_kernel(
    const float* __restrict__ x,
    const float* __restrict__ g,
    const float* __restrict__ b,
    unsigned short* __restrict__ out, int rows)
{
    int row  = blockIdx.x * 4 + (threadIdx.x >> 6);
    int lane = threadIdx.x & 63;
    if (row >= rows) return;
    const float* xr = x + (size_t)row * 512 + lane * 8;
    float4 d0 = *(const float4*)xr;
    float4 d1 = *(const float4*)(xr + 4);
    float v[8] = {d0.x, d0.y, d0.z, d0.w, d1.x, d1.y, d1.z, d1.w};
    float s = 0.f, ss = 0.f;
#pragma unroll
    for (int j = 0; j < 8; ++j) { s += v[j]; ss += v[j] * v[j]; }
#pragma unroll
    for (int o = 32; o > 0; o >>= 1) { s += __shfl_xor(s, o); ss += __shfl_xor(ss, o); }
    float mu   = s * (1.0f / 512.0f);
    float var  = ss * (1.0f / 512.0f) - mu * mu;
    var = fmaxf(var, 0.0f);
    float rstd = rsqrtf(var + 1e-5f);
    float4 g0 = *(const float4*)(g + lane * 8);
    float4 g1 = *(const float4*)(g + lane * 8 + 4);
    float4 b0 = *(const float4*)(b + lane * 8);
    float4 b1 = *(const float4*)(b + lane * 8 + 4);
    float gg[8] = {g0.x, g0.y, g0.z, g0.w, g1.x, g1.y, g1.z, g1.w};
    float bb[8] = {b0.x, b0.y, b0.z, b0.w, b1.x, b1.y, b1.z, b1.w};
    uint4 res; unsigned short* rs = (unsigned short*)&res;
#pragma unroll
    for (int j = 0; j < 8; ++j)
        rs[j] = f2b((v[j] - mu) * rstd * gg[j] + bb[j]);
    *(uint4*)(out + (size_t)row * 512 + lane * 8) = res;
}

// ---------------------------------------------------------------------------
// GEMM: C[M,N] = act(A[M,K](bf16) @ B[K,N](bf16) + bias(f32)) [+ res(f32)]
// out_f32: C is float*, else bf16 (unsigned short*).
// 64x64 block tile, BK=32, 4 waves each 32x32 via 2x2 16x16x32 mfma tiles.
// ---------------------------------------------------------------------------
__global__ __launch_bounds__(256) void gemm_bias_kernel(
    const unsigned short* __restrict__ A,
    const unsigned short* __restrict__ B,
    const float* __restrict__ bias,
    const float* __restrict__ residual,
    void* __restrict__ Cv,
    int M, int N, int K, int act_gelu, int out_f32)
{
    __shared__ unsigned short As[64][32];
    __shared__ unsigned short Bs[64][32];   // [n][k]

    int bm = blockIdx.y * 64;
    int bn = blockIdx.x * 64;
    int tid = threadIdx.x;
    int wave = tid >> 6, lane = tid & 63;
    int quad = lane >> 4, l16 = lane & 15;
    int wm = (wave >> 1) * 32, wn = (wave & 1) * 32;

    f32x4 acc[2][2] = {};

    int am = tid >> 2, ak = (tid & 3) * 8;
    int bk = tid >> 3, bnn = (tid & 7) * 8;

    for (int k0 = 0; k0 < K; k0 += 32) {
        *(uint4*)(&As[am][ak]) = *(const uint4*)(A + (size_t)(bm + am) * K + k0 + ak);
        uint4 bv = *(const uint4*)(B + (size_t)(k0 + bk) * N + bn + bnn);
        const unsigned short* bvs = (const unsigned short*)&bv;
#pragma unroll
        for (int j = 0; j < 8; ++j) Bs[bnn + j][bk] = bvs[j];
        __syncthreads();
#pragma unroll
        for (int i = 0; i < 2; ++i) {
            s16x8 af = *(const s16x8*)(&As[wm + i * 16 + l16][quad * 8]);
#pragma unroll
            for (int j = 0; j < 2; ++j) {
                s16x8 bf = *(const s16x8*)(&Bs[wn + j * 16 + l16][quad * 8]);
                acc[i][j] = __builtin_amdgcn_mfma_f32_16x16x32_bf16(af, bf, acc[i][j], 0, 0, 0);
            }
        }
        __syncthreads();
    }

#pragma unroll
    for (int i = 0; i < 2; ++i) {
#pragma unroll
        for (int j = 0; j < 2; ++j) {
#pragma unroll
            for (int r = 0; r < 4; ++r) {
                int row = bm + wm + i * 16 + quad * 4 + r;
                int col = bn + wn + j * 16 + l16;
                float val = acc[i][j][r] + bias[col];
                if (act_gelu) val = gelu_exact(val);
                if (residual) val += residual[(size_t)row * N + col];
                if (out_f32) ((float*)Cv)[(size_t)row * N + col] = val;
                else ((unsigned short*)Cv)[(size_t)row * N + col] = f2b(val);
            }
        }
    }
}

// ---------------------------------------------------------------------------
// Attention: one block per batch. q/k/v bf16, x residual f32, x2 out f32.
// ---------------------------------------------------------------------------
__global__ __launch_bounds__(256) void attn_kernel(
    const unsigned short* __restrict__ q,
    const unsigned short* __restrict__ k,
    const unsigned short* __restrict__ v,
    const float* __restrict__ x,
    float* __restrict__ x2)
{
    __shared__ unsigned short Ps[128][128];
    __shared__ unsigned short Vs[64][128];

    int b = blockIdx.x;
    int tid = threadIdx.x;
    int wave = tid >> 6, lane = tid & 63;
    int quad = lane >> 4, l16 = lane & 15;
    const size_t bo = (size_t)b * 128 * 512;
    const unsigned short* qb = q + bo;
    const unsigned short* kb = k + bo;
    const unsigned short* vb = v + bo;

    f32x4 acc[2][8] = {};
    for (int e0 = 0; e0 < 512; e0 += 32) {
        s16x8 a0 = *(const s16x8*)(qb + (size_t)(wave * 32 + l16) * 512 + e0 + quad * 8);
        s16x8 a1 = *(const s16x8*)(qb + (size_t)(wave * 32 + 16 + l16) * 512 + e0 + quad * 8);
#pragma unroll
        for (int j = 0; j < 8; ++j) {
            s16x8 bf = *(const s16x8*)(kb + (size_t)(j * 16 + l16) * 512 + e0 + quad * 8);
            acc[0][j] = __builtin_amdgcn_mfma_f32_16x16x32_bf16(a0, bf, acc[0][j], 0, 0, 0);
            acc[1][j] = __builtin_amdgcn_mfma_f32_16x16x32_bf16(a1, bf, acc[1][j], 0, 0, 0);
        }
    }

    const float NEG = -1e30f;
#pragma unroll
    for (int i = 0; i < 2; ++i) {
#pragma unroll
        for (int r = 0; r < 4; ++r) {
            int t = wave * 32 + i * 16 + quad * 4 + r;
            float m = NEG;
#pragma unroll
            for (int j = 0; j < 8; ++j) {
                int s_col = j * 16 + l16;
                float val = acc[i][j][r] * 0.125f;
                val = (s_col <= t) ? val : NEG;
                acc[i][j][r] = val;
                m = fmaxf(m, val);
            }
            for (int o = 1; o < 16; o <<= 1) m = fmaxf(m, __shfl_xor(m, o));
            float sm = 0.f;
#pragma unroll
            for (int j = 0; j < 8; ++j) {
                float e = __expf(acc[i][j][r] - m);
                acc[i][j][r] = e;
                sm += e;
            }
            for (int o = 1; o < 16; o <<= 1) sm += __shfl_xor(sm, o);
            float inv = 1.0f / sm;
#pragma unroll
            for (int j = 0; j < 8; ++j)
                Ps[t][j * 16 + l16] = f2b(acc[i][j][r] * inv);
        }
    }
    __syncthreads();

    const float* xb = x + bo;
    float* ob = x2 + bo;
    for (int e0 = 0; e0 < 512; e0 += 64) {
        if (e0) __syncthreads();
#pragma unroll
        for (int p = 0; p < 4; ++p) {
            int s = (tid >> 3) + p * 32;
            int c = (tid & 7) * 8;
            uint4 d = *(const uint4*)(vb + (size_t)s * 512 + e0 + c);
            const unsigned short* dsv = (const unsigned short*)&d;
#pragma unroll
            for (int j = 0; j < 8; ++j) Vs[c + j][s] = dsv[j];
        }
        __syncthreads();

        f32x4 acc2[2][4] = {};
#pragma unroll
        for (int ks = 0; ks < 4; ++ks) {
            s16x8 a0 = *(const s16x8*)(&Ps[wave * 32 + l16][ks * 32 + quad * 8]);
            s16x8 a1 = *(const s16x8*)(&Ps[wave * 32 + 16 + l16][ks * 32 + quad * 8]);
#pragma unroll
            for (int n = 0; n < 4; ++n) {
                s16x8 bf = *(const s16x8*)(&Vs[n * 16 + l16][ks * 32 + quad * 8]);
                acc2[0][n] = __builtin_amdgcn_mfma_f32_16x16x32_bf16(a0, bf, acc2[0][n], 0, 0, 0);
                acc2[1][n] = __builtin_amdgcn_mfma_f32_16x16x32_bf16(a1, bf, acc2[1][n], 0, 0, 0);
            }
        }
#pragma unroll
        for (int i = 0; i < 2; ++i) {
#pragma unroll
            for (int n = 0; n < 4; ++n) {
#pragma unroll
                for (int r = 0; r < 4; ++r) {
                    int t = wave * 32 + i * 16 + quad * 4 + r;
                    int e = e0 + n * 16 + l16;
                    ob[(size_t)t * 512 + e] = acc2[i][n][r] + xb[(size_t)t * 512 + e];
                }
            }
        }
    }
}

// ---------------------------------------------------------------------------
extern "C" void kernel_launch(void* const* d_in, const int* in_sizes, int n_in,
                              void* d_out, int out_size, void* d_ws, size_t ws_size,
                              hipStream_t stream) {
    // Inputs are f32, dict order (confirmed: d_in[0] is the unique 33.5M tensor).
    const float* x   = (const float*)d_in[0];
    const float* wq  = (const float*)d_in[1];
    const float* bq  = (const float*)d_in[2];
    const float* wk  = (const float*)d_in[3];
    const float* bk  = (const float*)d_in[4];
    const float* wv  = (const float*)d_in[5];
    const float* bv  = (const float*)d_in[6];
    const float* g1  = (const float*)d_in[7];
    const float* b1  = (const float*)d_in[8];
    const float* g2  = (const float*)d_in[9];
    const float* b2  = (const float*)d_in[10];
    const float* w1  = (const float*)d_in[11];
    const float* bm1 = (const float*)d_in[12];
    const float* w2  = (const float*)d_in[13];
    const float* bm2 = (const float*)d_in[14];
    float* out = (float*)d_out;          // reference output dtype is float32

    const int BATCH = 512, T = 128;
    dim3 blk(256);

    // ---- one-time weight conversion f32 -> bf16 (5.5 MB of ws) ----
    unsigned short* wqb = (unsigned short*)d_ws;
    unsigned short* wkb = wqb + 262144;
    unsigned short* wvb = wkb + 262144;
    unsigned short* w1b = wvb + 262144;
    unsigned short* w2b = w1b + 1048576;
    cvt_kernel<<<256,  blk, 0, stream>>>(wq, wqb, 262144);
    cvt_kernel<<<256,  blk, 0, stream>>>(wk, wkb, 262144);
    cvt_kernel<<<256,  blk, 0, stream>>>(wv, wvb, 262144);
    cvt_kernel<<<1024, blk, 0, stream>>>(w1, w1b, 1048576);
    cvt_kernel<<<1024, blk, 0, stream>>>(w2, w2b, 1048576);

    // ---- dynamic region: chunk batch so it fits ws ----
    // per-batch bytes: h bf16 (131072) + x2f f32 (262144) + slab (524288)
    //  = 917504; plus 5767168 B of converted weights.
    int C = 512;
    while (C > 1 && 5767168ull + (size_t)C * 917504ull > ws_size) C >>= 1;

    const int R = C * T;                 // rows per chunk
    const size_t S = (size_t)R * 512;    // elements per 512-wide row buffer
    char* dyn = (char*)(w2b + 1048576);
    unsigned short* h   = (unsigned short*)dyn;
    float*          x2f = (float*)(dyn + S * 2);
    unsigned short* qv  = (unsigned short*)(dyn + S * 2 + S * 4);
    unsigned short* q   = qv;
    unsigned short* kk  = qv + S;
    unsigned short* vv  = qv + 2 * S;
    unsigned short* mff = qv;            // aliases q/k/v after attention; 4*S elems

    for (int b0 = 0; b0 < BATCH; b0 += C) {
        const size_t off = (size_t)b0 * T * 512;
        // attention sub-block
        ln_kernel<<<R / 4, blk, 0, stream>>>(x + off, g1, b1, h, R);
        gemm_bias_kernel<<<dim3(8, R / 64), blk, 0, stream>>>(h, wqb, bq, nullptr, q,  R, 512, 512, 0, 0);
        gemm_bias_kernel<<<dim3(8, R / 64), blk, 0, stream>>>(h, wkb, bk, nullptr, kk, R, 512, 512, 0, 0);
        gemm_bias_kernel<<<dim3(8, R / 64), blk, 0, stream>>>(h, wvb, bv, nullptr, vv, R, 512, 512, 0, 0);
        attn_kernel<<<C, blk, 0, stream>>>(q, kk, vv, x + off, x2f);
        // MLP sub-block
        ln_kernel<<<R / 4, blk, 0, stream>>>(x2f, g2, b2, h, R);
        gemm_bias_kernel<<<dim3(32, R / 64), blk, 0, stream>>>(h, w1b, bm1, nullptr, mff, R, 2048, 512, 1, 0);
        gemm_bias_kernel<<<dim3(8, R / 64), blk, 0, stream>>>(mff, w2b, bm2, x2f, out + off, R, 512, 2048, 0, 1);
    }
}

// Round 6
// 1249.266 us; speedup vs baseline: 1.6497x; 1.6497x over previous
//
#include <hip/hip_runtime.h>
#include <hip/hip_bf16.h>
#include <math.h>

typedef __attribute__((ext_vector_type(8))) short s16x8;
typedef __attribute__((ext_vector_type(4))) float f32x4;

static __device__ __forceinline__ float b2f(unsigned short u) {
    union { unsigned int u; float f; } x; x.u = ((unsigned int)u) << 16; return x.f;
}
static __device__ __forceinline__ unsigned short f2b(float f) {
    __hip_bfloat16 h = __float2bfloat16(f);
    return *reinterpret_cast<unsigned short*>(&h);
}
static __device__ __forceinline__ float gelu_exact(float x) {
    return 0.5f * x * (1.0f + erff(x * 0.70710678118654752f));
}
// async global->LDS, 16B per lane. lds must be wave-uniform base; HW scatters
// lane i to base + i*16 (m97/m104). gptr is per-lane.
static __device__ __forceinline__ void gload16(void* lds, const void* g) {
    __builtin_amdgcn_global_load_lds(
        (const __attribute__((address_space(1))) unsigned int*)g,
        (__attribute__((address_space(3))) unsigned int*)lds, 16, 0, 0);
}

// ---------------------------------------------------------------------------
// Weight convert+transpose: W[K,N] f32 -> Wt[N,K] bf16. 32x32 LDS tiles.
// ---------------------------------------------------------------------------
__global__ __launch_bounds__(256) void cvt_t_kernel(
    const float* __restrict__ W, unsigned short* __restrict__ Wt, int K, int N)
{
    __shared__ unsigned short tile[32][33];
    int n0 = blockIdx.x * 32, k0 = blockIdx.y * 32;
    int tx = threadIdx.x & 31, ty = threadIdx.x >> 5;   // ty 0..7
#pragma unroll
    for (int p = 0; p < 32; p += 8)
        tile[tx][ty + p] = f2b(W[(size_t)(k0 + ty + p) * N + n0 + tx]);
    __syncthreads();
#pragma unroll
    for (int p = 0; p < 32; p += 8)
        Wt[(size_t)(n0 + ty + p) * K + k0 + tx] = tile[ty + p][tx];
}

// ---------------------------------------------------------------------------
// LayerNorm: f32 input rows of 512 -> bf16 output. One wave per row.
// ---------------------------------------------------------------------------
__global__ __launch_bounds__(256) void ln_kernel(
    const float* __restrict__ x,
    const float* __restrict__ g,
    const float* __restrict__ b,
    unsigned short* __restrict__ out, int rows)
{
    int row  = blockIdx.x * 4 + (threadIdx.x >> 6);
    int lane = threadIdx.x & 63;
    if (row >= rows) return;
    const float* xr = x + (size_t)row * 512 + lane * 8;
    float4 d0 = *(const float4*)xr;
    float4 d1 = *(const float4*)(xr + 4);
    float v[8] = {d0.x, d0.y, d0.z, d0.w, d1.x, d1.y, d1.z, d1.w};
    float s = 0.f, ss = 0.f;
#pragma unroll
    for (int j = 0; j < 8; ++j) { s += v[j]; ss += v[j] * v[j]; }
#pragma unroll
    for (int o = 32; o > 0; o >>= 1) { s += __shfl_xor(s, o); ss += __shfl_xor(ss, o); }
    float mu   = s * (1.0f / 512.0f);
    float var  = ss * (1.0f / 512.0f) - mu * mu;
    var = fmaxf(var, 0.0f);
    float rstd = rsqrtf(var + 1e-5f);
    float4 g0 = *(const float4*)(g + lane * 8);
    float4 g1 = *(const float4*)(g + lane * 8 + 4);
    float4 b0 = *(const float4*)(b + lane * 8);
    float4 b1 = *(const float4*)(b + lane * 8 + 4);
    float gg[8] = {g0.x, g0.y, g0.z, g0.w, g1.x, g1.y, g1.z, g1.w};
    float bb[8] = {b0.x, b0.y, b0.z, b0.w, b1.x, b1.y, b1.z, b1.w};
    uint4 res; unsigned short* rs = (unsigned short*)&res;
#pragma unroll
    for (int j = 0; j < 8; ++j)
        rs[j] = f2b((v[j] - mu) * rstd * gg[j] + bb[j]);
    *(uint4*)(out + (size_t)row * 512 + lane * 8) = res;
}

// ---------------------------------------------------------------------------
// m97-style GEMM: C[M,N] = act(A[M,K] @ Bt[N,K]^T + bias) [+ residual]
// 128x128 tile, BK=32, 4 waves x (64x64 via 4x4 16x16x32 mfma).
// LDS tiles staged with global_load_lds width=16; XOR swizzle
// (kgrp ^= (row>>1)&3) baked into staging source so ds_read_b128 fragment
// reads spread across all 8 bank groups (2 lanes/group = conflict-free).
// ---------------------------------------------------------------------------
__global__ __launch_bounds__(256) void gemm_bt_kernel(
    const unsigned short* __restrict__ A,    // [M,K] bf16
    const unsigned short* __restrict__ Bt,   // [N,K] bf16
    const float* __restrict__ bias,
    const float* __restrict__ residual,
    void* __restrict__ Cv,
    int M, int N, int K, int act_gelu, int out_f32)
{
    __shared__ unsigned short As[128 * 32];
    __shared__ unsigned short Bs[128 * 32];

    const int tid  = threadIdx.x;
    const int wave = tid >> 6, lane = tid & 63;
    const int quad = lane >> 4, l16 = lane & 15;
    const int bm = blockIdx.y * 128, bn = blockIdx.x * 128;
    const int wm = (wave >> 1) * 64, wn = (wave & 1) * 64;

    // staging: wave w, call c stages rows 16w+64c .. +16 of the tile.
    // lane i -> slot(row = 16w+64c+(i>>2), sgrp = i&3); source k-group is
    // swizzled: glog = sgrp ^ ((row>>1)&3)  (row+64 doesn't change the bits).
    const int srow = 16 * wave + (lane >> 2);
    const int sgrp = (lane & 3) ^ ((srow >> 1) & 3);
    const unsigned short* a_src = A  + (size_t)(bm + srow) * K + sgrp * 8;
    const unsigned short* b_src = Bt + (size_t)(bn + srow) * K + sgrp * 8;
    const size_t rowskip = (size_t)64 * K;
    unsigned short* ldsA = As + 512 * wave;       // bytes: 1024*wave
    unsigned short* ldsB = Bs + 512 * wave;

    // fragment-read swizzle: for r = wm+i*16+l16, (r>>1)&3 == (l16>>1)&3.
    const int axor = ((quad ^ ((l16 >> 1) & 3)) * 8);

    f32x4 acc[4][4] = {};

    for (int k0 = 0; k0 < K; k0 += 32) {
        gload16(ldsA,        a_src + k0);
        gload16(ldsA + 2048, a_src + rowskip + k0);
        gload16(ldsB,        b_src + k0);
        gload16(ldsB + 2048, b_src + rowskip + k0);
        __syncthreads();

        s16x8 af[4], bfr[4];
#pragma unroll
        for (int i = 0; i < 4; ++i)
            af[i] = *(const s16x8*)&As[(wm + i * 16 + l16) * 32 + axor];
#pragma unroll
        for (int j = 0; j < 4; ++j)
            bfr[j] = *(const s16x8*)&Bs[(wn + j * 16 + l16) * 32 + axor];
#pragma unroll
        for (int i = 0; i < 4; ++i)
#pragma unroll
            for (int j = 0; j < 4; ++j)
                acc[i][j] = __builtin_amdgcn_mfma_f32_16x16x32_bf16(af[i], bfr[j], acc[i][j], 0, 0, 0);
        __syncthreads();
    }

#pragma unroll
    for (int i = 0; i < 4; ++i) {
#pragma unroll
        for (int j = 0; j < 4; ++j) {
#pragma unroll
            for (int r = 0; r < 4; ++r) {
                int row = bm + wm + i * 16 + quad * 4 + r;
                int col = bn + wn + j * 16 + l16;
                float val = acc[i][j][r] + bias[col];
                if (act_gelu) val = gelu_exact(val);
                if (residual) val += residual[(size_t)row * N + col];
                if (out_f32) ((float*)Cv)[(size_t)row * N + col] = val;
                else ((unsigned short*)Cv)[(size_t)row * N + col] = f2b(val);
            }
        }
    }
}

// ---------------------------------------------------------------------------
// Attention: one block per batch. q/k/v bf16, x residual f32, x2 out f32.
// ---------------------------------------------------------------------------
__global__ __launch_bounds__(256) void attn_kernel(
    const unsigned short* __restrict__ q,
    const unsigned short* __restrict__ k,
    const unsigned short* __restrict__ v,
    const float* __restrict__ x,
    float* __restrict__ x2)
{
    __shared__ unsigned short Ps[128][128];
    __shared__ unsigned short Vs[64][128];

    int b = blockIdx.x;
    int tid = threadIdx.x;
    int wave = tid >> 6, lane = tid & 63;
    int quad = lane >> 4, l16 = lane & 15;
    const size_t bo = (size_t)b * 128 * 512;
    const unsigned short* qb = q + bo;
    const unsigned short* kb = k + bo;
    const unsigned short* vb = v + bo;

    f32x4 acc[2][8] = {};
    for (int e0 = 0; e0 < 512; e0 += 32) {
        s16x8 a0 = *(const s16x8*)(qb + (size_t)(wave * 32 + l16) * 512 + e0 + quad * 8);
        s16x8 a1 = *(const s16x8*)(qb + (size_t)(wave * 32 + 16 + l16) * 512 + e0 + quad * 8);
#pragma unroll
        for (int j = 0; j < 8; ++j) {
            s16x8 bf = *(const s16x8*)(kb + (size_t)(j * 16 + l16) * 512 + e0 + quad * 8);
            acc[0][j] = __builtin_amdgcn_mfma_f32_16x16x32_bf16(a0, bf, acc[0][j], 0, 0, 0);
            acc[1][j] = __builtin_amdgcn_mfma_f32_16x16x32_bf16(a1, bf, acc[1][j], 0, 0, 0);
        }
    }

    const float NEG = -1e30f;
#pragma unroll
    for (int i = 0; i < 2; ++i) {
#pragma unroll
        for (int r = 0; r < 4; ++r) {
            int t = wave * 32 + i * 16 + quad * 4 + r;
            float m = NEG;
#pragma unroll
            for (int j = 0; j < 8; ++j) {
                int s_col = j * 16 + l16;
                float val = acc[i][j][r] * 0.125f;
                val = (s_col <= t) ? val : NEG;
                acc[i][j][r] = val;
                m = fmaxf(m, val);
            }
            for (int o = 1; o < 16; o <<= 1) m = fmaxf(m, __shfl_xor(m, o));
            float sm = 0.f;
#pragma unroll
            for (int j = 0; j < 8; ++j) {
                float e = __expf(acc[i][j][r] - m);
                acc[i][j][r] = e;
                sm += e;
            }
            for (int o = 1; o < 16; o <<= 1) sm += __shfl_xor(sm, o);
            float inv = 1.0f / sm;
#pragma unroll
            for (int j = 0; j < 8; ++j)
                Ps[t][j * 16 + l16] = f2b(acc[i][j][r] * inv);
        }
    }
    __syncthreads();

    const float* xb = x + bo;
    float* ob = x2 + bo;
    for (int e0 = 0; e0 < 512; e0 += 64) {
        if (e0) __syncthreads();
#pragma unroll
        for (int p = 0; p < 4; ++p) {
            int s = (tid >> 3) + p * 32;
            int c = (tid & 7) * 8;
            uint4 d = *(const uint4*)(vb + (size_t)s * 512 + e0 + c);
            const unsigned short* dsv = (const unsigned short*)&d;
#pragma unroll
            for (int j = 0; j < 8; ++j) Vs[c + j][s] = dsv[j];
        }
        __syncthreads();

        f32x4 acc2[2][4] = {};
#pragma unroll
        for (int ks = 0; ks < 4; ++ks) {
            s16x8 a0 = *(const s16x8*)(&Ps[wave * 32 + l16][ks * 32 + quad * 8]);
            s16x8 a1 = *(const s16x8*)(&Ps[wave * 32 + 16 + l16][ks * 32 + quad * 8]);
#pragma unroll
            for (int n = 0; n < 4; ++n) {
                s16x8 bf = *(const s16x8*)(&Vs[n * 16 + l16][ks * 32 + quad * 8]);
                acc2[0][n] = __builtin_amdgcn_mfma_f32_16x16x32_bf16(a0, bf, acc2[0][n], 0, 0, 0);
                acc2[1][n] = __builtin_amdgcn_mfma_f32_16x16x32_bf16(a1, bf, acc2[1][n], 0, 0, 0);
            }
        }
#pragma unroll
        for (int i = 0; i < 2; ++i) {
#pragma unroll
            for (int n = 0; n < 4; ++n) {
#pragma unroll
                for (int r = 0; r < 4; ++r) {
                    int t = wave * 32 + i * 16 + quad * 4 + r;
                    int e = e0 + n * 16 + l16;
                    ob[(size_t)t * 512 + e] = acc2[i][n][r] + xb[(size_t)t * 512 + e];
                }
            }
        }
    }
}

// ---------------------------------------------------------------------------
extern "C" void kernel_launch(void* const* d_in, const int* in_sizes, int n_in,
                              void* d_out, int out_size, void* d_ws, size_t ws_size,
                              hipStream_t stream) {
    const float* x   = (const float*)d_in[0];
    const float* wq  = (const float*)d_in[1];
    const float* bq  = (const float*)d_in[2];
    const float* wk  = (const float*)d_in[3];
    const float* bk  = (const float*)d_in[4];
    const float* wv  = (const float*)d_in[5];
    const float* bv  = (const float*)d_in[6];
    const float* g1  = (const float*)d_in[7];
    const float* b1  = (const float*)d_in[8];
    const float* g2  = (const float*)d_in[9];
    const float* b2  = (const float*)d_in[10];
    const float* w1  = (const float*)d_in[11];
    const float* bm1 = (const float*)d_in[12];
    const float* w2  = (const float*)d_in[13];
    const float* bm2 = (const float*)d_in[14];
    float* out = (float*)d_out;          // reference output dtype is float32

    const int BATCH = 512, T = 128;
    dim3 blk(256);

    // ---- one-time weight convert+transpose f32[K,N] -> bf16[N,K] ----
    unsigned short* wqt = (unsigned short*)d_ws;
    unsigned short* wkt = wqt + 262144;
    unsigned short* wvt = wkt + 262144;
    unsigned short* w1t = wvt + 262144;   // [2048, 512]
    unsigned short* w2t = w1t + 1048576;  // [512, 2048]
    cvt_t_kernel<<<dim3(16, 16), blk, 0, stream>>>(wq, wqt, 512, 512);
    cvt_t_kernel<<<dim3(16, 16), blk, 0, stream>>>(wk, wkt, 512, 512);
    cvt_t_kernel<<<dim3(16, 16), blk, 0, stream>>>(wv, wvt, 512, 512);
    cvt_t_kernel<<<dim3(64, 16), blk, 0, stream>>>(w1, w1t, 512, 2048);
    cvt_t_kernel<<<dim3(16, 64), blk, 0, stream>>>(w2, w2t, 2048, 512);

    // ---- dynamic region: chunk batch so it fits ws ----
    // per-batch bytes: h bf16 (131072) + x2f f32 (262144) + slab (524288)
    //  = 917504; plus 5767168 B of converted weights.
    int C = 512;
    while (C > 1 && 5767168ull + (size_t)C * 917504ull > ws_size) C >>= 1;

    const int R = C * T;                 // rows per chunk (multiple of 128)
    const size_t S = (size_t)R * 512;    // elements per 512-wide row buffer
    char* dyn = (char*)(w2t + 1048576);
    unsigned short* h   = (unsigned short*)dyn;
    float*          x2f = (float*)(dyn + S * 2);
    unsigned short* qv  = (unsigned short*)(dyn + S * 2 + S * 4);
    unsigned short* q   = qv;
    unsigned short* kk  = qv + S;
    unsigned short* vv  = qv + 2 * S;
    unsigned short* mff = qv;            // aliases q/k/v after attention; 4*S elems

    for (int b0 = 0; b0 < BATCH; b0 += C) {
        const size_t off = (size_t)b0 * T * 512;
        // attention sub-block
        ln_kernel<<<R / 4, blk, 0, stream>>>(x + off, g1, b1, h, R);
        gemm_bt_kernel<<<dim3(4, R / 128), blk, 0, stream>>>(h, wqt, bq, nullptr, q,  R, 512, 512, 0, 0);
        gemm_bt_kernel<<<dim3(4, R / 128), blk, 0, stream>>>(h, wkt, bk, nullptr, kk, R, 512, 512, 0, 0);
        gemm_bt_kernel<<<dim3(4, R / 128), blk, 0, stream>>>(h, wvt, bv, nullptr, vv, R, 512, 512, 0, 0);
        attn_kernel<<<C, blk, 0, stream>>>(q, kk, vv, x + off, x2f);
        // MLP sub-block
        ln_kernel<<<R / 4, blk, 0, stream>>>(x2f, g2, b2, h, R);
        gemm_bt_kernel<<<dim3(16, R / 128), blk, 0, stream>>>(h, w1t, bm1, nullptr, mff, R, 2048, 512, 1, 0);
        gemm_bt_kernel<<<dim3(4, R / 128), blk, 0, stream>>>(mff, w2t, bm2, x2f, out + off, R, 512, 2048, 0, 1);
    }
}